// Round 1
// baseline (1373.139 us; speedup 1.0000x reference)
//
#include <hip/hip_runtime.h>

#define NB   32
#define NN   100000
#define NE   1000000
#define HD   64
#define AD   5
#define NL   3
#define NRL  231      // N_REL + 1
#define NTM  365
#define NOUT 228096   // 32 * 7128

// ---------------------------------------------------------------------------
// WT[c][k][h] = W_c[h][k], c: 0=Wf(pos) 1=Wn(zero) 2=Wp(neg)
__global__ __launch_bounds__(256) void prep_wt_kernel(
    const float* __restrict__ Wp, const float* __restrict__ Wn,
    const float* __restrict__ Wf, float* __restrict__ WT)
{
    int i = blockIdx.x * 256 + threadIdx.x;
    if (i >= 3 * 64 * 64) return;
    int c = i >> 12;
    int k = (i >> 6) & 63;
    int h = i & 63;
    const float* W = (c == 0) ? Wf : (c == 1 ? Wn : Wp);
    WT[i] = W[h * 64 + k];
}

// ---------------------------------------------------------------------------
// score[e] = sigmoid( relu([hid[src]|rel_e|q_e] @ W1.T) @ W2.T )
// thread-per-edge; W1/W2 wave-uniform -> scalar loads.
template <bool HZ>
__global__ __launch_bounds__(256) void score_kernel(
    const float* __restrict__ hidden,
    const float* __restrict__ rela,     // layer slice [231][64]
    const float* __restrict__ W1,       // layer slice [5][192]
    const float* __restrict__ W2,       // layer slice [5]
    const int*  __restrict__ src_idx,
    const int*  __restrict__ rel_idx,
    const int*  __restrict__ batch_idx,
    const int*  __restrict__ query_rel,
    float* __restrict__ score)
{
    int e = blockIdx.x * 256 + threadIdx.x;
    if (e >= NE) return;
    int rel = rel_idx[e];
    int q   = query_rel[batch_idx[e]];

    float s[AD] = {0.f, 0.f, 0.f, 0.f, 0.f};

    const float4* re = (const float4*)(rela + (size_t)rel * HD);
    #pragma unroll
    for (int j4 = 0; j4 < 16; ++j4) {
        float4 x = re[j4];
        #pragma unroll
        for (int a = 0; a < AD; ++a) {
            const float* w = W1 + a * 192 + 64 + j4 * 4;
            s[a] = fmaf(x.x, w[0], s[a]);
            s[a] = fmaf(x.y, w[1], s[a]);
            s[a] = fmaf(x.z, w[2], s[a]);
            s[a] = fmaf(x.w, w[3], s[a]);
        }
    }
    const float4* qe = (const float4*)(rela + (size_t)q * HD);
    #pragma unroll
    for (int j4 = 0; j4 < 16; ++j4) {
        float4 x = qe[j4];
        #pragma unroll
        for (int a = 0; a < AD; ++a) {
            const float* w = W1 + a * 192 + 128 + j4 * 4;
            s[a] = fmaf(x.x, w[0], s[a]);
            s[a] = fmaf(x.y, w[1], s[a]);
            s[a] = fmaf(x.z, w[2], s[a]);
            s[a] = fmaf(x.w, w[3], s[a]);
        }
    }
    if (!HZ) {
        int src = src_idx[e];
        const float4* hs = (const float4*)(hidden + (size_t)src * HD);
        #pragma unroll
        for (int j4 = 0; j4 < 16; ++j4) {
            float4 x = hs[j4];
            #pragma unroll
            for (int a = 0; a < AD; ++a) {
                const float* w = W1 + a * 192 + j4 * 4;
                s[a] = fmaf(x.x, w[0], s[a]);
                s[a] = fmaf(x.y, w[1], s[a]);
                s[a] = fmaf(x.z, w[2], s[a]);
                s[a] = fmaf(x.w, w[3], s[a]);
            }
        }
    }

    float z = 0.f;
    #pragma unroll
    for (int a = 0; a < AD; ++a) z = fmaf(fmaxf(s[a], 0.f), W2[a], z);
    score[e] = 1.f / (1.f + __expf(-z));
}

// ---------------------------------------------------------------------------
// agg[dst][cls][h] += score[e] * (hid[src][h] + rel_e[h] + t_emb[h])
// wave-per-edge, lane = h; edge scalars wave-uniform.
template <bool HZ>
__global__ __launch_bounds__(256) void scatter_kernel(
    const float* __restrict__ hidden,
    const float* __restrict__ rela,
    const float* __restrict__ temb,
    const float* __restrict__ score,
    const int*  __restrict__ src_idx,
    const int*  __restrict__ dst_idx,
    const int*  __restrict__ rel_idx,
    const int*  __restrict__ rel_time,
    float* __restrict__ agg)            // [N][3][64]
{
    int lane = threadIdx.x & 63;
    int wid  = blockIdx.x * 4 + (threadIdx.x >> 6);
    wid = __builtin_amdgcn_readfirstlane(wid);
    int nw = gridDim.x * 4;

    for (int e = wid; e < NE; e += nw) {
        int   dst = dst_idx[e];
        int   rel = rel_idx[e];
        int   rt  = rel_time[e];
        float sc  = score[e];
        int cls = (rt > 0) ? 0 : ((rt == 0) ? 1 : 2);
        int ta  = (rt < 0) ? -rt : rt;
        float v = rela[(size_t)rel * HD + lane] + temb[(size_t)ta * HD + lane];
        if (!HZ) {
            int src = src_idx[e];
            v += hidden[(size_t)src * HD + lane];
        }
        atomicAdd(&agg[((size_t)dst * 3 + cls) * HD + lane], sc * v);
    }
}

// ---------------------------------------------------------------------------
// hidden[n][h] = relu( sum_c agg[n][c][:] @ W_c.T )
// 64 nodes per block (128 threads); LDS transposed stage; weights in SGPRs.
__global__ __launch_bounds__(128) void transform_kernel(
    const float* __restrict__ agg,      // [N][192]
    const float* __restrict__ WT,       // [192][64]  (= [c][k][h])
    float* __restrict__ hidden)
{
    __shared__ float lds_t[192 * 64];
    int t    = threadIdx.x;
    int lane = t & 63;
    int half = __builtin_amdgcn_readfirstlane(t >> 6);  // 0 or 1
    int node0 = blockIdx.x * 64;

    for (int idx = t; idx < 64 * 48; idx += 128) {
        int node = idx & 63;
        int k4   = idx >> 6;
        float4 v = make_float4(0.f, 0.f, 0.f, 0.f);
        if (node0 + node < NN)
            v = *(const float4*)(agg + (size_t)(node0 + node) * 192 + k4 * 4);
        int kk = k4 * 4;
        lds_t[(kk + 0) * 64 + node] = v.x;
        lds_t[(kk + 1) * 64 + node] = v.y;
        lds_t[(kk + 2) * 64 + node] = v.z;
        lds_t[(kk + 3) * 64 + node] = v.w;
    }
    __syncthreads();

    float acc[32];
    #pragma unroll
    for (int hh = 0; hh < 32; ++hh) acc[hh] = 0.f;
    int half32 = half * 32;

    #pragma unroll 2
    for (int kk = 0; kk < 192; ++kk) {
        float a = lds_t[kk * 64 + lane];
        const float* __restrict__ w = WT + kk * 64 + half32;
        #pragma unroll
        for (int hh = 0; hh < 32; ++hh) acc[hh] = fmaf(a, w[hh], acc[hh]);
    }

    int node = node0 + lane;
    if (node < NN) {
        float* out = hidden + (size_t)node * 64 + half32;
        #pragma unroll
        for (int qd = 0; qd < 8; ++qd) {
            float4 v = make_float4(fmaxf(acc[qd * 4 + 0], 0.f),
                                   fmaxf(acc[qd * 4 + 1], 0.f),
                                   fmaxf(acc[qd * 4 + 2], 0.f),
                                   fmaxf(acc[qd * 4 + 3], 0.f));
            *(float4*)(out + qd * 4) = v;
        }
    }
}

// ---------------------------------------------------------------------------
// out[n] = dot(hidden[n], Wc) + bc for n < N, else 0
__global__ __launch_bounds__(256) void out_kernel(
    const float* __restrict__ hidden,
    const float* __restrict__ Wc,
    const float* __restrict__ bc,
    float* __restrict__ out)
{
    int i = blockIdx.x * 256 + threadIdx.x;
    if (i >= NOUT) return;
    float r = 0.f;
    if (i < NN) {
        const float4* h4 = (const float4*)(hidden + (size_t)i * 64);
        const float4* w4 = (const float4*)Wc;
        float acc = 0.f;
        #pragma unroll
        for (int q = 0; q < 16; ++q) {
            float4 hv = h4[q], wv = w4[q];
            acc = fmaf(hv.x, wv.x, acc);
            acc = fmaf(hv.y, wv.y, acc);
            acc = fmaf(hv.z, wv.z, acc);
            acc = fmaf(hv.w, wv.w, acc);
        }
        r = acc + bc[0];
    }
    out[i] = r;
}

// ---------------------------------------------------------------------------
extern "C" void kernel_launch(void* const* d_in, const int* in_sizes, int n_in,
                              void* d_out, int out_size, void* d_ws, size_t ws_size,
                              hipStream_t stream)
{
    const int*   batch_idx  = (const int*)d_in[0];
    const int*   src_idx    = (const int*)d_in[1];
    const int*   dst_idx    = (const int*)d_in[2];
    const int*   rel_idx    = (const int*)d_in[3];
    const int*   rel_time   = (const int*)d_in[4];
    const int*   query_rel  = (const int*)d_in[5];
    // d_in[6] out_batch, d_in[7] out_ent: layout is identity (n//NENT, n%NENT) — unused
    const float* rela_embed = (const float*)d_in[8];   // [3][231][64]
    const float* time_embed = (const float*)d_in[9];   // [365][64]
    const float* Wp         = (const float*)d_in[10];
    const float* Wn         = (const float*)d_in[11];
    const float* Wf         = (const float*)d_in[12];
    const float* W1         = (const float*)d_in[13];  // [3][5][192]
    const float* W2         = (const float*)d_in[14];  // [3][1][5]
    const float* Wc         = (const float*)d_in[15];  // [64]
    const float* bc         = (const float*)d_in[16];  // [1]
    float* out = (float*)d_out;

    char* ws = (char*)d_ws;
    float* hidden = (float*)(ws);                         // 25,600,000 B
    float* agg    = (float*)(ws + 25600000);              // 76,800,000 B
    float* score  = (float*)(ws + 102400000);             //  4,000,000 B
    float* WT     = (float*)(ws + 106400000);             //     49,152 B

    prep_wt_kernel<<<48, 256, 0, stream>>>(Wp, Wn, Wf, WT);

    for (int i = 0; i < NL; ++i) {
        hipMemsetAsync(agg, 0, (size_t)NN * 3 * HD * sizeof(float), stream);
        const float* rela = rela_embed + (size_t)i * NRL * HD;
        const float* W1i  = W1 + (size_t)i * AD * 192;
        const float* W2i  = W2 + (size_t)i * AD;
        if (i == 0) {
            score_kernel<true><<<(NE + 255) / 256, 256, 0, stream>>>(
                hidden, rela, W1i, W2i, src_idx, rel_idx, batch_idx, query_rel, score);
            scatter_kernel<true><<<4096, 256, 0, stream>>>(
                hidden, rela, time_embed, score, src_idx, dst_idx, rel_idx, rel_time, agg);
        } else {
            score_kernel<false><<<(NE + 255) / 256, 256, 0, stream>>>(
                hidden, rela, W1i, W2i, src_idx, rel_idx, batch_idx, query_rel, score);
            scatter_kernel<false><<<4096, 256, 0, stream>>>(
                hidden, rela, time_embed, score, src_idx, dst_idx, rel_idx, rel_time, agg);
        }
        transform_kernel<<<(NN + 63) / 64, 128, 0, stream>>>(agg, WT, hidden);
    }

    out_kernel<<<(NOUT + 255) / 256, 256, 0, stream>>>(hidden, Wc, bc, out);
}

// Round 3
// 1126.904 us; speedup vs baseline: 1.2185x; 1.2185x over previous
//
#include <hip/hip_runtime.h>

#define NB   32
#define NN   100000
#define NE   1000000
#define HD   64
#define AD   5
#define NL   3
#define NRL  231      // N_REL + 1
#define NTM  365
#define NOUT 228096   // 32 * 7128
#define NBLK1 391     // ceil(NN/256)

// ---------------------------------------------------------------------------
// WT[c][k][h] = W_c[h][k], c: 0=Wf(pos) 1=Wn(zero) 2=Wp(neg)
__global__ __launch_bounds__(256) void prep_wt_kernel(
    const float* __restrict__ Wp, const float* __restrict__ Wn,
    const float* __restrict__ Wf, float* __restrict__ WT)
{
    int i = blockIdx.x * 256 + threadIdx.x;
    if (i >= 3 * 64 * 64) return;
    int c = i >> 12;
    int k = (i >> 6) & 63;
    int h = i & 63;
    const float* W = (c == 0) ? Wf : (c == 1 ? Wn : Wp);
    WT[i] = W[h * 64 + k];
}

// ---------------------------------------------------------------------------
// Counting sort by dst: histogram
__global__ __launch_bounds__(256) void hist_kernel(
    const int* __restrict__ dst_idx, int* __restrict__ deg)
{
    int e = blockIdx.x * 256 + threadIdx.x;
    if (e < NE) atomicAdd(&deg[dst_idx[e]], 1);
}

// per-block inclusive scan of deg (256/block)
__global__ __launch_bounds__(256) void scan1_kernel(
    const int* __restrict__ deg, int* __restrict__ tmp, int* __restrict__ bsum)
{
    __shared__ int s[256];
    int tid = threadIdx.x;
    int i = blockIdx.x * 256 + tid;
    int v = (i < NN) ? deg[i] : 0;
    s[tid] = v;
    __syncthreads();
    #pragma unroll
    for (int st = 1; st < 256; st <<= 1) {
        int t = (tid >= st) ? s[tid - st] : 0;
        __syncthreads();
        s[tid] += t;
        __syncthreads();
    }
    if (i < NN) tmp[i] = s[tid];
    if (tid == 255) bsum[blockIdx.x] = s[255];
}

// scan block sums (exclusive), single block of 512
__global__ __launch_bounds__(512) void scan2_kernel(
    const int* __restrict__ bsum, int* __restrict__ bpref)
{
    __shared__ int s[512];
    int tid = threadIdx.x;
    int v = (tid < NBLK1) ? bsum[tid] : 0;
    s[tid] = v;
    __syncthreads();
    #pragma unroll
    for (int st = 1; st < 512; st <<= 1) {
        int t = (tid >= st) ? s[tid - st] : 0;
        __syncthreads();
        s[tid] += t;
        __syncthreads();
    }
    if (tid < NBLK1) bpref[tid] = s[tid] - v;  // exclusive
}

// finalize: off[n+1] = inclusive sum, off[0]=0, cursor[n] = exclusive sum
__global__ __launch_bounds__(256) void scan3_kernel(
    const int* __restrict__ deg, const int* __restrict__ tmp,
    const int* __restrict__ bpref, int* __restrict__ off, int* __restrict__ cursor)
{
    int i = blockIdx.x * 256 + threadIdx.x;
    if (i >= NN) return;
    int incl = tmp[i] + bpref[i >> 8];
    off[i + 1] = incl;
    cursor[i] = incl - deg[i];
    if (i == 0) off[0] = 0;
}

// scatter edges into dst-sorted order, pre-gathering per-edge metadata
__global__ __launch_bounds__(256) void sort_scatter_kernel(
    const int* __restrict__ dst_idx, const int* __restrict__ src_idx,
    const int* __restrict__ rel_idx, const int* __restrict__ rel_time,
    const int* __restrict__ batch_idx, const int* __restrict__ query_rel,
    int* __restrict__ cursor,
    int* __restrict__ srt_src, int* __restrict__ srt_rel,
    int* __restrict__ srt_q, int* __restrict__ srt_ct)
{
    int e = blockIdx.x * 256 + threadIdx.x;
    if (e >= NE) return;
    int d = dst_idx[e];
    int pos = atomicAdd(&cursor[d], 1);
    int rt = rel_time[e];
    int cls = (rt > 0) ? 0 : ((rt == 0) ? 1 : 2);
    int ta = (rt < 0) ? -rt : rt;
    srt_src[pos] = src_idx[e];
    srt_rel[pos] = rel_idx[e];
    srt_q[pos]   = query_rel[batch_idx[e]];
    srt_ct[pos]  = (cls << 9) | ta;
}

// ---------------------------------------------------------------------------
// score[j] = sigmoid( relu([hid[src]|rel_e|q_e] @ W1.T) @ W2.T )  (sorted order)
template <bool HZ>
__global__ __launch_bounds__(256) void score_kernel(
    const float* __restrict__ hidden,
    const float* __restrict__ rela,     // layer slice [231][64]
    const float* __restrict__ W1,       // layer slice [5][192]
    const float* __restrict__ W2,       // layer slice [5]
    const int*  __restrict__ srt_src,
    const int*  __restrict__ srt_rel,
    const int*  __restrict__ srt_q,
    float* __restrict__ score)
{
    int j = blockIdx.x * 256 + threadIdx.x;
    if (j >= NE) return;
    int rel = srt_rel[j];
    int q   = srt_q[j];

    float s[AD] = {0.f, 0.f, 0.f, 0.f, 0.f};

    const float4* re = (const float4*)(rela + (size_t)rel * HD);
    #pragma unroll
    for (int j4 = 0; j4 < 16; ++j4) {
        float4 x = re[j4];
        #pragma unroll
        for (int a = 0; a < AD; ++a) {
            const float* w = W1 + a * 192 + 64 + j4 * 4;
            s[a] = fmaf(x.x, w[0], s[a]);
            s[a] = fmaf(x.y, w[1], s[a]);
            s[a] = fmaf(x.z, w[2], s[a]);
            s[a] = fmaf(x.w, w[3], s[a]);
        }
    }
    const float4* qe = (const float4*)(rela + (size_t)q * HD);
    #pragma unroll
    for (int j4 = 0; j4 < 16; ++j4) {
        float4 x = qe[j4];
        #pragma unroll
        for (int a = 0; a < AD; ++a) {
            const float* w = W1 + a * 192 + 128 + j4 * 4;
            s[a] = fmaf(x.x, w[0], s[a]);
            s[a] = fmaf(x.y, w[1], s[a]);
            s[a] = fmaf(x.z, w[2], s[a]);
            s[a] = fmaf(x.w, w[3], s[a]);
        }
    }
    if (!HZ) {
        int src = srt_src[j];
        const float4* hs = (const float4*)(hidden + (size_t)src * HD);
        #pragma unroll
        for (int j4 = 0; j4 < 16; ++j4) {
            float4 x = hs[j4];
            #pragma unroll
            for (int a = 0; a < AD; ++a) {
                const float* w = W1 + a * 192 + j4 * 4;
                s[a] = fmaf(x.x, w[0], s[a]);
                s[a] = fmaf(x.y, w[1], s[a]);
                s[a] = fmaf(x.z, w[2], s[a]);
                s[a] = fmaf(x.w, w[3], s[a]);
            }
        }
    }

    float z = 0.f;
    #pragma unroll
    for (int a = 0; a < AD; ++a) z = fmaf(fmaxf(s[a], 0.f), W2[a], z);
    score[j] = 1.f / (1.f + __expf(-z));
}

// ---------------------------------------------------------------------------
// Fused segmented-reduce + transform.
// Block = 4 waves handles a 64-node tile; wave w reduces nodes [w*16, w*16+16),
// stages 192-vectors into LDS [k][node] (pitch 65, conflict-free), then all
// waves transform: wave w computes h in [w*16, w*16+16) for all 64 nodes,
// weights WT via wave-uniform s_loads.
// NOTE: hidden_in and hidden_out MUST be distinct buffers (cross-block race
// otherwise — this was R2's correctness bug).
#define LPITCH 65
template <bool HZ>
__global__ __launch_bounds__(256) void reduce_transform_kernel(
    const float* __restrict__ hidden_in,
    const float* __restrict__ rela,     // layer slice [231][64]
    const float* __restrict__ temb,     // [365][64]
    const float* __restrict__ score,    // [E] sorted
    const int*  __restrict__ srt_src,
    const int*  __restrict__ srt_rel,
    const int*  __restrict__ srt_ct,
    const int*  __restrict__ off,       // [NN+1]
    const float* __restrict__ WT,       // [192][64]
    float* __restrict__ hidden_out)
{
    __shared__ float lds_t[192 * LPITCH];
    int tid  = threadIdx.x;
    int lane = tid & 63;
    int w    = __builtin_amdgcn_readfirstlane(tid >> 6);  // 0..3
    int node0 = blockIdx.x * 64;

    for (int r = 0; r < 16; ++r) {
        int nl = w * 16 + r;                  // node column 0..63
        int node = node0 + nl;
        float a0 = 0.f, a1 = 0.f, a2 = 0.f;
        if (node < NN) {
            int off0 = __builtin_amdgcn_readfirstlane(off[node]);
            int off1 = __builtin_amdgcn_readfirstlane(off[node + 1]);
            for (int base = off0; base < off1; base += 64) {
                int j = base + lane;
                bool val = (j < off1);
                float sc = val ? score[j]   : 0.f;
                int irel = val ? srt_rel[j] : 0;
                int ict  = val ? srt_ct[j]  : 0;
                int isrc = 0;
                if (!HZ) isrc = val ? srt_src[j] : 0;
                int cnt = off1 - base; if (cnt > 64) cnt = 64;
                for (int i = 0; i < cnt; ++i) {
                    float sci = __uint_as_float(
                        __builtin_amdgcn_readlane(__float_as_uint(sc), i));
                    int reli = __builtin_amdgcn_readlane(irel, i);
                    int cti  = __builtin_amdgcn_readlane(ict, i);
                    float v = rela[(size_t)reli * HD + lane]
                            + temb[(size_t)(cti & 511) * HD + lane];
                    if (!HZ) {
                        int srci = __builtin_amdgcn_readlane(isrc, i);
                        v += hidden_in[(size_t)srci * HD + lane];
                    }
                    float m = sci * v;
                    int c = cti >> 9;
                    if (c == 0)      a0 += m;
                    else if (c == 1) a1 += m;
                    else             a2 += m;
                }
            }
        }
        lds_t[(0 * 64 + lane) * LPITCH + nl] = a0;
        lds_t[(1 * 64 + lane) * LPITCH + nl] = a1;
        lds_t[(2 * 64 + lane) * LPITCH + nl] = a2;
    }
    __syncthreads();

    // transform: out[node=lane][h0+i] = sum_k lds_t[k][lane] * WT[k][h0+i]
    float acc[16];
    #pragma unroll
    for (int i = 0; i < 16; ++i) acc[i] = 0.f;
    int h0 = w * 16;
    const float* __restrict__ Wb = WT + h0;

    #pragma unroll 4
    for (int k = 0; k < 192; ++k) {
        float a = lds_t[k * LPITCH + lane];
        #pragma unroll
        for (int i = 0; i < 16; ++i)
            acc[i] = fmaf(a, Wb[k * 64 + i], acc[i]);
    }

    int node = node0 + lane;
    if (node < NN) {
        float* out = hidden_out + (size_t)node * 64 + h0;
        #pragma unroll
        for (int qd = 0; qd < 4; ++qd) {
            float4 v = make_float4(fmaxf(acc[qd * 4 + 0], 0.f),
                                   fmaxf(acc[qd * 4 + 1], 0.f),
                                   fmaxf(acc[qd * 4 + 2], 0.f),
                                   fmaxf(acc[qd * 4 + 3], 0.f));
            *(float4*)(out + qd * 4) = v;
        }
    }
}

// ---------------------------------------------------------------------------
// out[n] = dot(hidden[n], Wc) + bc for n < N, else 0
__global__ __launch_bounds__(256) void out_kernel(
    const float* __restrict__ hidden,
    const float* __restrict__ Wc,
    const float* __restrict__ bc,
    float* __restrict__ out)
{
    int i = blockIdx.x * 256 + threadIdx.x;
    if (i >= NOUT) return;
    float r = 0.f;
    if (i < NN) {
        const float4* h4 = (const float4*)(hidden + (size_t)i * 64);
        const float4* w4 = (const float4*)Wc;
        float acc = 0.f;
        #pragma unroll
        for (int q = 0; q < 16; ++q) {
            float4 hv = h4[q], wv = w4[q];
            acc = fmaf(hv.x, wv.x, acc);
            acc = fmaf(hv.y, wv.y, acc);
            acc = fmaf(hv.z, wv.z, acc);
            acc = fmaf(hv.w, wv.w, acc);
        }
        r = acc + bc[0];
    }
    out[i] = r;
}

// ---------------------------------------------------------------------------
extern "C" void kernel_launch(void* const* d_in, const int* in_sizes, int n_in,
                              void* d_out, int out_size, void* d_ws, size_t ws_size,
                              hipStream_t stream)
{
    const int*   batch_idx  = (const int*)d_in[0];
    const int*   src_idx    = (const int*)d_in[1];
    const int*   dst_idx    = (const int*)d_in[2];
    const int*   rel_idx    = (const int*)d_in[3];
    const int*   rel_time   = (const int*)d_in[4];
    const int*   query_rel  = (const int*)d_in[5];
    const float* rela_embed = (const float*)d_in[8];   // [3][231][64]
    const float* time_embed = (const float*)d_in[9];   // [365][64]
    const float* Wp         = (const float*)d_in[10];
    const float* Wn         = (const float*)d_in[11];
    const float* Wf         = (const float*)d_in[12];
    const float* W1         = (const float*)d_in[13];  // [3][5][192]
    const float* W2         = (const float*)d_in[14];  // [3][1][5]
    const float* Wc         = (const float*)d_in[15];  // [64]
    const float* bc         = (const float*)d_in[16];  // [1]
    float* out = (float*)d_out;

    char* ws = (char*)d_ws;
    float* hid0    = (float*)(ws + 0);                    // 25.6 MB
    float* hid1    = (float*)(ws + 26000000);             // 25.6 MB
    float* score   = (float*)(ws + 52000000);             //  4.0 MB
    float* WT      = (float*)(ws + 56000000);             //  48 KB
    int*   deg     = (int*)  (ws + 56100000);             // 400 KB
    int*   off     = (int*)  (ws + 56600000);             // 400 KB
    int*   cursor  = (int*)  (ws + 57100000);             // 400 KB
    int*   tmp     = (int*)  (ws + 57600000);             // 400 KB
    int*   bsum    = (int*)  (ws + 58100000);             // 2 KB
    int*   bpref   = (int*)  (ws + 58110000);             // 2 KB
    int*   srt_src = (int*)  (ws + 58200000);             // 4 MB
    int*   srt_rel = (int*)  (ws + 62200000);             // 4 MB
    int*   srt_q   = (int*)  (ws + 66200000);             // 4 MB
    int*   srt_ct  = (int*)  (ws + 70200000);             // 4 MB

    prep_wt_kernel<<<48, 256, 0, stream>>>(Wp, Wn, Wf, WT);

    // --- counting sort by dst ---
    hipMemsetAsync(deg, 0, NN * sizeof(int), stream);
    hist_kernel<<<(NE + 255) / 256, 256, 0, stream>>>(dst_idx, deg);
    scan1_kernel<<<NBLK1, 256, 0, stream>>>(deg, tmp, bsum);
    scan2_kernel<<<1, 512, 0, stream>>>(bsum, bpref);
    scan3_kernel<<<NBLK1, 256, 0, stream>>>(deg, tmp, bpref, off, cursor);
    sort_scatter_kernel<<<(NE + 255) / 256, 256, 0, stream>>>(
        dst_idx, src_idx, rel_idx, rel_time, batch_idx, query_rel,
        cursor, srt_src, srt_rel, srt_q, srt_ct);

    // --- layers (ping-pong hidden: h_in -> h_out, distinct buffers) ---
    // L0: (unused) -> hid0 ; L1: hid0 -> hid1 ; L2: hid1 -> hid0
    {
        const float* rela = rela_embed;
        score_kernel<true><<<(NE + 255) / 256, 256, 0, stream>>>(
            hid0, rela, W1, W2, srt_src, srt_rel, srt_q, score);
        reduce_transform_kernel<true><<<(NN + 63) / 64, 256, 0, stream>>>(
            hid1, rela, time_embed, score, srt_src, srt_rel, srt_ct,
            off, WT, hid0);
    }
    for (int i = 1; i < NL; ++i) {
        const float* rela = rela_embed + (size_t)i * NRL * HD;
        const float* W1i  = W1 + (size_t)i * AD * 192;
        const float* W2i  = W2 + (size_t)i * AD;
        const float* hin  = (i == 1) ? hid0 : hid1;
        float*       hout = (i == 1) ? hid1 : hid0;
        score_kernel<false><<<(NE + 255) / 256, 256, 0, stream>>>(
            hin, rela, W1i, W2i, srt_src, srt_rel, srt_q, score);
        reduce_transform_kernel<false><<<(NN + 63) / 64, 256, 0, stream>>>(
            hin, rela, time_embed, score, srt_src, srt_rel, srt_ct,
            off, WT, hout);
    }

    out_kernel<<<(NOUT + 255) / 256, 256, 0, stream>>>(hid0, Wc, bc, out);
}

// Round 4
// 681.561 us; speedup vs baseline: 2.0147x; 1.6534x over previous
//
#include <hip/hip_runtime.h>

#define NB   32
#define NN   100000
#define NE   1000000
#define HD   64
#define AD   5
#define NL   3
#define NRL  231      // N_REL + 1
#define NTM  365
#define NOUT 228096   // 32 * 7128
#define NBLK1 391     // ceil(NN/256)

// meta packing: w0 = src | (rel<<17) | (cls<<25) ; w1 = ta | (q<<9)

// ---------------------------------------------------------------------------
// WT[c][k][h] = W_c[h][k], c: 0=Wf(pos) 1=Wn(zero) 2=Wp(neg)
__global__ __launch_bounds__(256) void prep_wt_kernel(
    const float* __restrict__ Wp, const float* __restrict__ Wn,
    const float* __restrict__ Wf, float* __restrict__ WT)
{
    int i = blockIdx.x * 256 + threadIdx.x;
    if (i >= 3 * 64 * 64) return;
    int c = i >> 12;
    int k = (i >> 6) & 63;
    int h = i & 63;
    const float* W = (c == 0) ? Wf : (c == 1 ? Wn : Wp);
    WT[i] = W[h * 64 + k];
}

// ---------------------------------------------------------------------------
// T_rel[l][r][a] = sum_k W1[l][a][64+k]*rela[l][r][k]
// T_q  [l][r][a] = sum_k W1[l][a][128+k]*rela[l][r][k]
__global__ __launch_bounds__(256) void prep_tables_kernel(
    const float* __restrict__ rela_embed,   // [3][231][64]
    const float* __restrict__ W1,           // [3][5][192]
    float* __restrict__ Trel,               // [3][231][8]
    float* __restrict__ Tq)                 // [3][231][8]
{
    int l = blockIdx.x;
    int r = threadIdx.x;
    if (r >= NRL) return;
    const float4* rrow = (const float4*)(rela_embed + ((size_t)l * NRL + r) * HD);
    const float* W1l = W1 + (size_t)l * AD * 192;
    float tr[AD] = {0,0,0,0,0}, tq[AD] = {0,0,0,0,0};
    #pragma unroll
    for (int k4 = 0; k4 < 16; ++k4) {
        float4 x = rrow[k4];
        #pragma unroll
        for (int a = 0; a < AD; ++a) {
            const float* wr = W1l + a * 192 + 64 + k4 * 4;
            const float* wq = W1l + a * 192 + 128 + k4 * 4;
            tr[a] = fmaf(x.x, wr[0], tr[a]); tr[a] = fmaf(x.y, wr[1], tr[a]);
            tr[a] = fmaf(x.z, wr[2], tr[a]); tr[a] = fmaf(x.w, wr[3], tr[a]);
            tq[a] = fmaf(x.x, wq[0], tq[a]); tq[a] = fmaf(x.y, wq[1], tq[a]);
            tq[a] = fmaf(x.z, wq[2], tq[a]); tq[a] = fmaf(x.w, wq[3], tq[a]);
        }
    }
    float* tro = Trel + ((size_t)l * NRL + r) * 8;
    float* tqo = Tq   + ((size_t)l * NRL + r) * 8;
    #pragma unroll
    for (int a = 0; a < AD; ++a) { tro[a] = tr[a]; tqo[a] = tq[a]; }
    tro[5] = tro[6] = tro[7] = 0.f;
    tqo[5] = tqo[6] = tqo[7] = 0.f;
}

// ---------------------------------------------------------------------------
// proj[n][a] = sum_k W1[a][k] * hidden[n][k]   (W1 cols 0..63)
__global__ __launch_bounds__(256) void proj_kernel(
    const float* __restrict__ hidden,
    const float* __restrict__ W1l,      // layer slice [5][192]
    float* __restrict__ proj)           // [NN][8]
{
    int n = blockIdx.x * 256 + threadIdx.x;
    if (n >= NN) return;
    const float4* h4 = (const float4*)(hidden + (size_t)n * HD);
    float acc[AD] = {0,0,0,0,0};
    #pragma unroll
    for (int k4 = 0; k4 < 16; ++k4) {
        float4 x = h4[k4];
        #pragma unroll
        for (int a = 0; a < AD; ++a) {
            const float* w = W1l + a * 192 + k4 * 4;
            acc[a] = fmaf(x.x, w[0], acc[a]); acc[a] = fmaf(x.y, w[1], acc[a]);
            acc[a] = fmaf(x.z, w[2], acc[a]); acc[a] = fmaf(x.w, w[3], acc[a]);
        }
    }
    float* o = proj + (size_t)n * 8;
    #pragma unroll
    for (int a = 0; a < AD; ++a) o[a] = acc[a];
    o[5] = o[6] = o[7] = 0.f;
}

// ---------------------------------------------------------------------------
// Counting sort by dst
__global__ __launch_bounds__(256) void hist_kernel(
    const int* __restrict__ dst_idx, int* __restrict__ deg)
{
    int e = blockIdx.x * 256 + threadIdx.x;
    if (e < NE) atomicAdd(&deg[dst_idx[e]], 1);
}

__global__ __launch_bounds__(256) void scan1_kernel(
    const int* __restrict__ deg, int* __restrict__ tmp, int* __restrict__ bsum)
{
    __shared__ int s[256];
    int tid = threadIdx.x;
    int i = blockIdx.x * 256 + tid;
    int v = (i < NN) ? deg[i] : 0;
    s[tid] = v;
    __syncthreads();
    #pragma unroll
    for (int st = 1; st < 256; st <<= 1) {
        int t = (tid >= st) ? s[tid - st] : 0;
        __syncthreads();
        s[tid] += t;
        __syncthreads();
    }
    if (i < NN) tmp[i] = s[tid];
    if (tid == 255) bsum[blockIdx.x] = s[255];
}

__global__ __launch_bounds__(512) void scan2_kernel(
    const int* __restrict__ bsum, int* __restrict__ bpref)
{
    __shared__ int s[512];
    int tid = threadIdx.x;
    int v = (tid < NBLK1) ? bsum[tid] : 0;
    s[tid] = v;
    __syncthreads();
    #pragma unroll
    for (int st = 1; st < 512; st <<= 1) {
        int t = (tid >= st) ? s[tid - st] : 0;
        __syncthreads();
        s[tid] += t;
        __syncthreads();
    }
    if (tid < NBLK1) bpref[tid] = s[tid] - v;  // exclusive
}

__global__ __launch_bounds__(256) void scan3_kernel(
    const int* __restrict__ deg, const int* __restrict__ tmp,
    const int* __restrict__ bpref, int* __restrict__ off, int* __restrict__ cursor)
{
    int i = blockIdx.x * 256 + threadIdx.x;
    if (i >= NN) return;
    int incl = tmp[i] + bpref[i >> 8];
    off[i + 1] = incl;
    cursor[i] = incl - deg[i];
    if (i == 0) off[0] = 0;
}

__global__ __launch_bounds__(256) void sort_scatter_kernel(
    const int* __restrict__ dst_idx, const int* __restrict__ src_idx,
    const int* __restrict__ rel_idx, const int* __restrict__ rel_time,
    const int* __restrict__ batch_idx, const int* __restrict__ query_rel,
    int* __restrict__ cursor, int2* __restrict__ meta)
{
    int e = blockIdx.x * 256 + threadIdx.x;
    if (e >= NE) return;
    int d = dst_idx[e];
    int pos = atomicAdd(&cursor[d], 1);
    int rt = rel_time[e];
    int cls = (rt > 0) ? 0 : ((rt == 0) ? 1 : 2);
    int ta = (rt < 0) ? -rt : rt;
    int q = query_rel[batch_idx[e]];
    int2 m;
    m.x = src_idx[e] | (rel_idx[e] << 17) | (cls << 25);
    m.y = ta | (q << 9);
    meta[pos] = m;
}

// ---------------------------------------------------------------------------
// score[j] = sigmoid( sum_a relu(proj[src][a]+Trel[rel][a]+Tq[q][a]) * W2[a] )
template <bool HZ>
__global__ __launch_bounds__(256) void score_kernel(
    const float* __restrict__ proj,     // [NN][8]
    const float* __restrict__ Trel,     // layer slice [231][8]
    const float* __restrict__ Tq,       // layer slice [231][8]
    const float* __restrict__ W2,       // layer slice [5]
    const int2* __restrict__ meta,
    float* __restrict__ score)
{
    int j = blockIdx.x * 256 + threadIdx.x;
    if (j >= NE) return;
    int2 mt = meta[j];
    int rel = (mt.x >> 17) & 0xFF;
    int q   = (mt.y >> 9) & 0xFF;

    float4 t0 = *(const float4*)(Trel + rel * 8);
    float  t4 = Trel[rel * 8 + 4];
    float4 u0 = *(const float4*)(Tq + q * 8);
    float  u4 = Tq[q * 8 + 4];
    float4 p0 = make_float4(0.f, 0.f, 0.f, 0.f);
    float  p4 = 0.f;
    if (!HZ) {
        int src = mt.x & 0x1FFFF;
        p0 = *(const float4*)(proj + (size_t)src * 8);
        p4 = proj[(size_t)src * 8 + 4];
    }
    float z = 0.f;
    z = fmaf(fmaxf(p0.x + t0.x + u0.x, 0.f), W2[0], z);
    z = fmaf(fmaxf(p0.y + t0.y + u0.y, 0.f), W2[1], z);
    z = fmaf(fmaxf(p0.z + t0.z + u0.z, 0.f), W2[2], z);
    z = fmaf(fmaxf(p0.w + t0.w + u0.w, 0.f), W2[3], z);
    z = fmaf(fmaxf(p4   + t4   + u4,   0.f), W2[4], z);
    score[j] = 1.f / (1.f + __expf(-z));
}

// ---------------------------------------------------------------------------
// Fused segmented-reduce + transform, lane-parallel edges.
// Block = 4 waves = 64-node tile. Wave = 4 groups of 16 lanes; group g handles
// nodes {g, g+4, g+8, g+12} of the wave's 16-node strip... (here: wave w owns
// node columns w*16..w*16+15; within the wave, group g takes nl = w*16+rr*4+g).
// Lane covers h = hc*4..hc*4+3 as float4. No cross-lane combine needed.
#define LPITCH 65
template <bool HZ>
__global__ __launch_bounds__(256) void reduce_transform_kernel(
    const float* __restrict__ hidden_in,
    const float* __restrict__ rela,     // layer slice [231][64]
    const float* __restrict__ temb,     // [365][64]
    const float* __restrict__ score,    // [E] sorted
    const int2* __restrict__ meta,      // [E] sorted
    const int*  __restrict__ off,       // [NN+1]
    const float* __restrict__ WT,       // [192][64]
    float* __restrict__ hidden_out)
{
    __shared__ float lds_t[192 * LPITCH];
    int tid  = threadIdx.x;
    int lane = tid & 63;
    int w    = __builtin_amdgcn_readfirstlane(tid >> 6);  // 0..3
    int g    = lane >> 4;                                  // 0..3
    int hc   = lane & 15;                                  // 0..15
    int node0 = blockIdx.x * 64;

    for (int rr = 0; rr < 4; ++rr) {
        int nl = w * 16 + rr * 4 + g;        // node column 0..63
        int node = node0 + nl;
        float4 a0 = make_float4(0,0,0,0);
        float4 a1 = make_float4(0,0,0,0);
        float4 a2 = make_float4(0,0,0,0);
        if (node < NN) {
            int o0 = off[node];
            int o1 = off[node + 1];
            if (o0 < o1) {
                int2 mt = meta[o0];
                float sc = score[o0];
                for (int j = o0; j < o1; ++j) {
                    int jn = (j + 1 < o1) ? j + 1 : o1 - 1;
                    int2 mtn = meta[jn];          // prefetch next
                    float scn = score[jn];
                    int src = mt.x & 0x1FFFF;
                    int rel = (mt.x >> 17) & 0xFF;
                    int cls = (mt.x >> 25) & 3;
                    int ta  = mt.y & 511;
                    float4 rv = *(const float4*)(rela + rel * HD + hc * 4);
                    float4 tv = *(const float4*)(temb + ta * HD + hc * 4);
                    float vx = rv.x + tv.x, vy = rv.y + tv.y;
                    float vz = rv.z + tv.z, vw = rv.w + tv.w;
                    if (!HZ) {
                        float4 hv = *(const float4*)(hidden_in + (size_t)src * HD + hc * 4);
                        vx += hv.x; vy += hv.y; vz += hv.z; vw += hv.w;
                    }
                    float s0 = (cls == 0) ? sc : 0.f;
                    float s1 = (cls == 1) ? sc : 0.f;
                    float s2 = (cls == 2) ? sc : 0.f;
                    a0.x = fmaf(s0, vx, a0.x); a0.y = fmaf(s0, vy, a0.y);
                    a0.z = fmaf(s0, vz, a0.z); a0.w = fmaf(s0, vw, a0.w);
                    a1.x = fmaf(s1, vx, a1.x); a1.y = fmaf(s1, vy, a1.y);
                    a1.z = fmaf(s1, vz, a1.z); a1.w = fmaf(s1, vw, a1.w);
                    a2.x = fmaf(s2, vx, a2.x); a2.y = fmaf(s2, vy, a2.y);
                    a2.z = fmaf(s2, vz, a2.z); a2.w = fmaf(s2, vw, a2.w);
                    mt = mtn; sc = scn;
                }
            }
        }
        int kb = hc * 4;
        lds_t[(0 * 64 + kb + 0) * LPITCH + nl] = a0.x;
        lds_t[(0 * 64 + kb + 1) * LPITCH + nl] = a0.y;
        lds_t[(0 * 64 + kb + 2) * LPITCH + nl] = a0.z;
        lds_t[(0 * 64 + kb + 3) * LPITCH + nl] = a0.w;
        lds_t[(1 * 64 + kb + 0) * LPITCH + nl] = a1.x;
        lds_t[(1 * 64 + kb + 1) * LPITCH + nl] = a1.y;
        lds_t[(1 * 64 + kb + 2) * LPITCH + nl] = a1.z;
        lds_t[(1 * 64 + kb + 3) * LPITCH + nl] = a1.w;
        lds_t[(2 * 64 + kb + 0) * LPITCH + nl] = a2.x;
        lds_t[(2 * 64 + kb + 1) * LPITCH + nl] = a2.y;
        lds_t[(2 * 64 + kb + 2) * LPITCH + nl] = a2.z;
        lds_t[(2 * 64 + kb + 3) * LPITCH + nl] = a2.w;
    }
    __syncthreads();

    // transform: out[node=lane][h0+i] = sum_k lds_t[k][lane] * WT[k][h0+i]
    float acc[16];
    #pragma unroll
    for (int i = 0; i < 16; ++i) acc[i] = 0.f;
    int h0 = w * 16;
    const float* __restrict__ Wb = WT + h0;

    #pragma unroll 4
    for (int k = 0; k < 192; ++k) {
        float a = lds_t[k * LPITCH + lane];
        #pragma unroll
        for (int i = 0; i < 16; ++i)
            acc[i] = fmaf(a, Wb[k * 64 + i], acc[i]);
    }

    int node = node0 + lane;
    if (node < NN) {
        float* out = hidden_out + (size_t)node * 64 + h0;
        #pragma unroll
        for (int qd = 0; qd < 4; ++qd) {
            float4 v = make_float4(fmaxf(acc[qd * 4 + 0], 0.f),
                                   fmaxf(acc[qd * 4 + 1], 0.f),
                                   fmaxf(acc[qd * 4 + 2], 0.f),
                                   fmaxf(acc[qd * 4 + 3], 0.f));
            *(float4*)(out + qd * 4) = v;
        }
    }
}

// ---------------------------------------------------------------------------
__global__ __launch_bounds__(256) void out_kernel(
    const float* __restrict__ hidden,
    const float* __restrict__ Wc,
    const float* __restrict__ bc,
    float* __restrict__ out)
{
    int i = blockIdx.x * 256 + threadIdx.x;
    if (i >= NOUT) return;
    float r = 0.f;
    if (i < NN) {
        const float4* h4 = (const float4*)(hidden + (size_t)i * 64);
        const float4* w4 = (const float4*)Wc;
        float acc = 0.f;
        #pragma unroll
        for (int q = 0; q < 16; ++q) {
            float4 hv = h4[q], wv = w4[q];
            acc = fmaf(hv.x, wv.x, acc);
            acc = fmaf(hv.y, wv.y, acc);
            acc = fmaf(hv.z, wv.z, acc);
            acc = fmaf(hv.w, wv.w, acc);
        }
        r = acc + bc[0];
    }
    out[i] = r;
}

// ---------------------------------------------------------------------------
extern "C" void kernel_launch(void* const* d_in, const int* in_sizes, int n_in,
                              void* d_out, int out_size, void* d_ws, size_t ws_size,
                              hipStream_t stream)
{
    const int*   batch_idx  = (const int*)d_in[0];
    const int*   src_idx    = (const int*)d_in[1];
    const int*   dst_idx    = (const int*)d_in[2];
    const int*   rel_idx    = (const int*)d_in[3];
    const int*   rel_time   = (const int*)d_in[4];
    const int*   query_rel  = (const int*)d_in[5];
    const float* rela_embed = (const float*)d_in[8];   // [3][231][64]
    const float* time_embed = (const float*)d_in[9];   // [365][64]
    const float* Wp         = (const float*)d_in[10];
    const float* Wn         = (const float*)d_in[11];
    const float* Wf         = (const float*)d_in[12];
    const float* W1         = (const float*)d_in[13];  // [3][5][192]
    const float* W2         = (const float*)d_in[14];  // [3][1][5]
    const float* Wc         = (const float*)d_in[15];  // [64]
    const float* bc         = (const float*)d_in[16];  // [1]
    float* out = (float*)d_out;

    char* ws = (char*)d_ws;
    float* hid0   = (float*)(ws + 0);            // 25.6 MB
    float* hid1   = (float*)(ws + 25600000);     // 25.6 MB
    float* score  = (float*)(ws + 51200000);     //  4.0 MB
    float* WT     = (float*)(ws + 55200000);     //  48 KB
    float* proj   = (float*)(ws + 55300000);     //  3.2 MB
    float* Trel   = (float*)(ws + 58600000);     //  ~22 KB
    float* Tq     = (float*)(ws + 58630000);     //  ~22 KB
    int*   off    = (int*)  (ws + 58660000);     // 400 KB
    int2*  meta   = (int2*) (ws + 59100000);     //  8.0 MB
    // sort temps alias the score region (dead before first score write)
    int*   deg    = (int*)((char*)score + 0);
    int*   tmp    = (int*)((char*)score + 400000);
    int*   cursor = (int*)((char*)score + 800000);
    int*   bsum   = (int*)((char*)score + 1200000);
    int*   bpref  = (int*)((char*)score + 1210000);

    prep_wt_kernel<<<48, 256, 0, stream>>>(Wp, Wn, Wf, WT);
    prep_tables_kernel<<<NL, 256, 0, stream>>>(rela_embed, W1, Trel, Tq);

    // --- counting sort by dst ---
    hipMemsetAsync(deg, 0, NN * sizeof(int), stream);
    hist_kernel<<<(NE + 255) / 256, 256, 0, stream>>>(dst_idx, deg);
    scan1_kernel<<<NBLK1, 256, 0, stream>>>(deg, tmp, bsum);
    scan2_kernel<<<1, 512, 0, stream>>>(bsum, bpref);
    scan3_kernel<<<NBLK1, 256, 0, stream>>>(deg, tmp, bpref, off, cursor);
    sort_scatter_kernel<<<(NE + 255) / 256, 256, 0, stream>>>(
        dst_idx, src_idx, rel_idx, rel_time, batch_idx, query_rel,
        cursor, meta);

    // --- layers (ping-pong: L0 -> hid0, L1 hid0->hid1, L2 hid1->hid0) ---
    for (int i = 0; i < NL; ++i) {
        const float* rela = rela_embed + (size_t)i * NRL * HD;
        const float* W1i  = W1 + (size_t)i * AD * 192;
        const float* W2i  = W2 + (size_t)i * AD;
        const float* Tri  = Trel + (size_t)i * NRL * 8;
        const float* Tqi  = Tq   + (size_t)i * NRL * 8;
        const float* hin  = (i == 1) ? hid0 : hid1;   // unused for i==0
        float*       hout = (i == 0) ? hid0 : ((i == 1) ? hid1 : hid0);
        if (i == 0) {
            score_kernel<true><<<(NE + 255) / 256, 256, 0, stream>>>(
                proj, Tri, Tqi, W2i, meta, score);
            reduce_transform_kernel<true><<<(NN + 63) / 64, 256, 0, stream>>>(
                hin, rela, time_embed, score, meta, off, WT, hout);
        } else {
            proj_kernel<<<(NN + 255) / 256, 256, 0, stream>>>(hin, W1i, proj);
            score_kernel<false><<<(NE + 255) / 256, 256, 0, stream>>>(
                proj, Tri, Tqi, W2i, meta, score);
            reduce_transform_kernel<false><<<(NN + 63) / 64, 256, 0, stream>>>(
                hin, rela, time_embed, score, meta, off, WT, hout);
        }
    }

    out_kernel<<<(NOUT + 255) / 256, 256, 0, stream>>>(hid0, Wc, bc, out);
}

// Round 5
// 539.905 us; speedup vs baseline: 2.5433x; 1.2624x over previous
//
#include <hip/hip_runtime.h>

#define NB   32
#define NN   100000
#define NE   1000000
#define HD   64
#define AD   5
#define NL   3
#define NRL  231      // N_REL + 1
#define NTM  365
#define NOUT 228096   // 32 * 7128
#define NBLK1 391     // ceil(NN/256)

// meta packing: w0 = src | (rel<<17) | (cls<<25) ; w1 = ta | (q<<9)

// ---------------------------------------------------------------------------
// WT[c][k][h] = W_c[h][k], c: 0=Wf(pos) 1=Wn(zero) 2=Wp(neg)
__global__ __launch_bounds__(256) void prep_wt_kernel(
    const float* __restrict__ Wp, const float* __restrict__ Wn,
    const float* __restrict__ Wf, float* __restrict__ WT)
{
    int i = blockIdx.x * 256 + threadIdx.x;
    if (i >= 3 * 64 * 64) return;
    int c = i >> 12;
    int k = (i >> 6) & 63;
    int h = i & 63;
    const float* W = (c == 0) ? Wf : (c == 1 ? Wn : Wp);
    WT[i] = W[h * 64 + k];
}

// ---------------------------------------------------------------------------
__global__ __launch_bounds__(256) void prep_tables_kernel(
    const float* __restrict__ rela_embed,   // [3][231][64]
    const float* __restrict__ W1,           // [3][5][192]
    float* __restrict__ Trel,               // [3][231][8]
    float* __restrict__ Tq)                 // [3][231][8]
{
    int l = blockIdx.x;
    int r = threadIdx.x;
    if (r >= NRL) return;
    const float4* rrow = (const float4*)(rela_embed + ((size_t)l * NRL + r) * HD);
    const float* W1l = W1 + (size_t)l * AD * 192;
    float tr[AD] = {0,0,0,0,0}, tq[AD] = {0,0,0,0,0};
    #pragma unroll
    for (int k4 = 0; k4 < 16; ++k4) {
        float4 x = rrow[k4];
        #pragma unroll
        for (int a = 0; a < AD; ++a) {
            const float* wr = W1l + a * 192 + 64 + k4 * 4;
            const float* wq = W1l + a * 192 + 128 + k4 * 4;
            tr[a] = fmaf(x.x, wr[0], tr[a]); tr[a] = fmaf(x.y, wr[1], tr[a]);
            tr[a] = fmaf(x.z, wr[2], tr[a]); tr[a] = fmaf(x.w, wr[3], tr[a]);
            tq[a] = fmaf(x.x, wq[0], tq[a]); tq[a] = fmaf(x.y, wq[1], tq[a]);
            tq[a] = fmaf(x.z, wq[2], tq[a]); tq[a] = fmaf(x.w, wq[3], tq[a]);
        }
    }
    float* tro = Trel + ((size_t)l * NRL + r) * 8;
    float* tqo = Tq   + ((size_t)l * NRL + r) * 8;
    #pragma unroll
    for (int a = 0; a < AD; ++a) { tro[a] = tr[a]; tqo[a] = tq[a]; }
    tro[5] = tro[6] = tro[7] = 0.f;
    tqo[5] = tqo[6] = tqo[7] = 0.f;
}

// ---------------------------------------------------------------------------
// proj[n][a] = sum_k W1[a][k] * hidden[n][k]
__global__ __launch_bounds__(256) void proj_kernel(
    const float* __restrict__ hidden,
    const float* __restrict__ W1l,
    float* __restrict__ proj)           // [NN][8]
{
    int n = blockIdx.x * 256 + threadIdx.x;
    if (n >= NN) return;
    const float4* h4 = (const float4*)(hidden + (size_t)n * HD);
    float acc[AD] = {0,0,0,0,0};
    #pragma unroll
    for (int k4 = 0; k4 < 16; ++k4) {
        float4 x = h4[k4];
        #pragma unroll
        for (int a = 0; a < AD; ++a) {
            const float* w = W1l + a * 192 + k4 * 4;
            acc[a] = fmaf(x.x, w[0], acc[a]); acc[a] = fmaf(x.y, w[1], acc[a]);
            acc[a] = fmaf(x.z, w[2], acc[a]); acc[a] = fmaf(x.w, w[3], acc[a]);
        }
    }
    float* o = proj + (size_t)n * 8;
    #pragma unroll
    for (int a = 0; a < AD; ++a) o[a] = acc[a];
    o[5] = o[6] = o[7] = 0.f;
}

// ---------------------------------------------------------------------------
// Counting sort by dst
__global__ __launch_bounds__(256) void hist_kernel(
    const int* __restrict__ dst_idx, int* __restrict__ deg)
{
    int e = blockIdx.x * 256 + threadIdx.x;
    if (e < NE) atomicAdd(&deg[dst_idx[e]], 1);
}

__global__ __launch_bounds__(256) void scan1_kernel(
    const int* __restrict__ deg, int* __restrict__ tmp, int* __restrict__ bsum)
{
    __shared__ int s[256];
    int tid = threadIdx.x;
    int i = blockIdx.x * 256 + tid;
    int v = (i < NN) ? deg[i] : 0;
    s[tid] = v;
    __syncthreads();
    #pragma unroll
    for (int st = 1; st < 256; st <<= 1) {
        int t = (tid >= st) ? s[tid - st] : 0;
        __syncthreads();
        s[tid] += t;
        __syncthreads();
    }
    if (i < NN) tmp[i] = s[tid];
    if (tid == 255) bsum[blockIdx.x] = s[255];
}

__global__ __launch_bounds__(512) void scan2_kernel(
    const int* __restrict__ bsum, int* __restrict__ bpref)
{
    __shared__ int s[512];
    int tid = threadIdx.x;
    int v = (tid < NBLK1) ? bsum[tid] : 0;
    s[tid] = v;
    __syncthreads();
    #pragma unroll
    for (int st = 1; st < 512; st <<= 1) {
        int t = (tid >= st) ? s[tid - st] : 0;
        __syncthreads();
        s[tid] += t;
        __syncthreads();
    }
    if (tid < NBLK1) bpref[tid] = s[tid] - v;  // exclusive
}

__global__ __launch_bounds__(256) void scan3_kernel(
    const int* __restrict__ deg, const int* __restrict__ tmp,
    const int* __restrict__ bpref, int* __restrict__ off, int* __restrict__ cursor)
{
    int i = blockIdx.x * 256 + threadIdx.x;
    if (i >= NN) return;
    int incl = tmp[i] + bpref[i >> 8];
    off[i + 1] = incl;
    cursor[i] = incl - deg[i];
    if (i == 0) off[0] = 0;
}

__global__ __launch_bounds__(256) void sort_scatter_kernel(
    const int* __restrict__ dst_idx, const int* __restrict__ src_idx,
    const int* __restrict__ rel_idx, const int* __restrict__ rel_time,
    const int* __restrict__ batch_idx, const int* __restrict__ query_rel,
    int* __restrict__ cursor, int2* __restrict__ meta)
{
    int e = blockIdx.x * 256 + threadIdx.x;
    if (e >= NE) return;
    int d = dst_idx[e];
    int pos = atomicAdd(&cursor[d], 1);
    int rt = rel_time[e];
    int cls = (rt > 0) ? 0 : ((rt == 0) ? 1 : 2);
    int ta = (rt < 0) ? -rt : rt;
    int q = query_rel[batch_idx[e]];
    int2 m;
    m.x = src_idx[e] | (rel_idx[e] << 17) | (cls << 25);
    m.y = ta | (q << 9);
    meta[pos] = m;
}

// ---------------------------------------------------------------------------
// score[j] = sigmoid( sum_a relu(proj[src][a]+Trel[rel][a]+Tq[q][a]) * W2[a] )
template <bool HZ>
__global__ __launch_bounds__(256) void score_kernel(
    const float* __restrict__ proj,
    const float* __restrict__ Trel,
    const float* __restrict__ Tq,
    const float* __restrict__ W2,
    const int2* __restrict__ meta,
    float* __restrict__ score)
{
    int j = blockIdx.x * 256 + threadIdx.x;
    if (j >= NE) return;
    int2 mt = meta[j];
    int rel = (mt.x >> 17) & 0xFF;
    int q   = (mt.y >> 9) & 0xFF;

    float4 t0 = *(const float4*)(Trel + rel * 8);
    float  t4 = Trel[rel * 8 + 4];
    float4 u0 = *(const float4*)(Tq + q * 8);
    float  u4 = Tq[q * 8 + 4];
    float4 p0 = make_float4(0.f, 0.f, 0.f, 0.f);
    float  p4 = 0.f;
    if (!HZ) {
        int src = mt.x & 0x1FFFF;
        p0 = *(const float4*)(proj + (size_t)src * 8);
        p4 = proj[(size_t)src * 8 + 4];
    }
    float z = 0.f;
    z = fmaf(fmaxf(p0.x + t0.x + u0.x, 0.f), W2[0], z);
    z = fmaf(fmaxf(p0.y + t0.y + u0.y, 0.f), W2[1], z);
    z = fmaf(fmaxf(p0.z + t0.z + u0.z, 0.f), W2[2], z);
    z = fmaf(fmaxf(p0.w + t0.w + u0.w, 0.f), W2[3], z);
    z = fmaf(fmaxf(p4   + t4   + u4,   0.f), W2[4], z);
    score[j] = 1.f / (1.f + __expf(-z));
}

// ---------------------------------------------------------------------------
// Fused segmented-reduce + transform, class-sequential LDS (16.6 KB).
// Block = 4 waves = 64-node tile; wave w owns node cols w*16..w*16+15;
// group g (16 lanes) reduces nodes nl = w*16+rr*4+g, rr=0..3, keeping all
// 3 class accumulators in registers (a[4][3] float4). Edge loop unrolled x2
// for memory-level parallelism. Transform runs per class: stage 64 k-slices
// to LDS (pitch 65), 64 FMA rounds into acc[16], repeat for 3 classes.
// hidden_in / hidden_out must be distinct buffers.
#define LPITCH 65
template <bool HZ>
__global__ __launch_bounds__(256, 4) void reduce_transform_kernel(
    const float* __restrict__ hidden_in,
    const float* __restrict__ rela,     // layer slice [231][64]
    const float* __restrict__ temb,     // [365][64]
    const float* __restrict__ score,    // [E] sorted
    const int2* __restrict__ meta,      // [E] sorted
    const int*  __restrict__ off,       // [NN+1]
    const float* __restrict__ WT,       // [192][64]
    float* __restrict__ hidden_out)
{
    __shared__ float lds_t[64 * LPITCH];   // one class slab at a time
    int tid  = threadIdx.x;
    int lane = tid & 63;
    int w    = __builtin_amdgcn_readfirstlane(tid >> 6);  // 0..3
    int g    = lane >> 4;                                  // 0..3
    int hc   = lane & 15;                                  // 0..15
    int hc4  = hc * 4;
    int node0 = blockIdx.x * 64;

    float4 a[4][3];
    #pragma unroll
    for (int rr = 0; rr < 4; ++rr)
        #pragma unroll
        for (int c = 0; c < 3; ++c)
            a[rr][c] = make_float4(0.f, 0.f, 0.f, 0.f);

    #pragma unroll
    for (int rr = 0; rr < 4; ++rr) {
        int nl = w * 16 + rr * 4 + g;        // node column 0..63
        int node = node0 + nl;
        if (node >= NN) continue;
        int o0 = off[node];
        int o1 = off[node + 1];
        int j = o0;
        for (; j + 2 <= o1; j += 2) {
            int2 m0 = meta[j];
            int2 m1 = meta[j + 1];
            float sc0 = score[j];
            float sc1 = score[j + 1];
            int src0 = m0.x & 0x1FFFF, rel0 = (m0.x >> 17) & 0xFF;
            int cl0  = (m0.x >> 25) & 3, ta0 = m0.y & 511;
            int src1 = m1.x & 0x1FFFF, rel1 = (m1.x >> 17) & 0xFF;
            int cl1  = (m1.x >> 25) & 3, ta1 = m1.y & 511;
            float4 rv0 = *(const float4*)(rela + rel0 * HD + hc4);
            float4 tv0 = *(const float4*)(temb + ta0 * HD + hc4);
            float4 rv1 = *(const float4*)(rela + rel1 * HD + hc4);
            float4 tv1 = *(const float4*)(temb + ta1 * HD + hc4);
            float vx0 = rv0.x + tv0.x, vy0 = rv0.y + tv0.y;
            float vz0 = rv0.z + tv0.z, vw0 = rv0.w + tv0.w;
            float vx1 = rv1.x + tv1.x, vy1 = rv1.y + tv1.y;
            float vz1 = rv1.z + tv1.z, vw1 = rv1.w + tv1.w;
            if (!HZ) {
                float4 hv0 = *(const float4*)(hidden_in + (size_t)src0 * HD + hc4);
                float4 hv1 = *(const float4*)(hidden_in + (size_t)src1 * HD + hc4);
                vx0 += hv0.x; vy0 += hv0.y; vz0 += hv0.z; vw0 += hv0.w;
                vx1 += hv1.x; vy1 += hv1.y; vz1 += hv1.z; vw1 += hv1.w;
            }
            float sA0 = (cl0 == 0) ? sc0 : 0.f;
            float sB0 = (cl0 == 1) ? sc0 : 0.f;
            float sC0 = (cl0 == 2) ? sc0 : 0.f;
            float sA1 = (cl1 == 0) ? sc1 : 0.f;
            float sB1 = (cl1 == 1) ? sc1 : 0.f;
            float sC1 = (cl1 == 2) ? sc1 : 0.f;
            a[rr][0].x = fmaf(sA0, vx0, a[rr][0].x); a[rr][0].y = fmaf(sA0, vy0, a[rr][0].y);
            a[rr][0].z = fmaf(sA0, vz0, a[rr][0].z); a[rr][0].w = fmaf(sA0, vw0, a[rr][0].w);
            a[rr][1].x = fmaf(sB0, vx0, a[rr][1].x); a[rr][1].y = fmaf(sB0, vy0, a[rr][1].y);
            a[rr][1].z = fmaf(sB0, vz0, a[rr][1].z); a[rr][1].w = fmaf(sB0, vw0, a[rr][1].w);
            a[rr][2].x = fmaf(sC0, vx0, a[rr][2].x); a[rr][2].y = fmaf(sC0, vy0, a[rr][2].y);
            a[rr][2].z = fmaf(sC0, vz0, a[rr][2].z); a[rr][2].w = fmaf(sC0, vw0, a[rr][2].w);
            a[rr][0].x = fmaf(sA1, vx1, a[rr][0].x); a[rr][0].y = fmaf(sA1, vy1, a[rr][0].y);
            a[rr][0].z = fmaf(sA1, vz1, a[rr][0].z); a[rr][0].w = fmaf(sA1, vw1, a[rr][0].w);
            a[rr][1].x = fmaf(sB1, vx1, a[rr][1].x); a[rr][1].y = fmaf(sB1, vy1, a[rr][1].y);
            a[rr][1].z = fmaf(sB1, vz1, a[rr][1].z); a[rr][1].w = fmaf(sB1, vw1, a[rr][1].w);
            a[rr][2].x = fmaf(sC1, vx1, a[rr][2].x); a[rr][2].y = fmaf(sC1, vy1, a[rr][2].y);
            a[rr][2].z = fmaf(sC1, vz1, a[rr][2].z); a[rr][2].w = fmaf(sC1, vw1, a[rr][2].w);
        }
        if (j < o1) {
            int2 m0 = meta[j];
            float sc0 = score[j];
            int src0 = m0.x & 0x1FFFF, rel0 = (m0.x >> 17) & 0xFF;
            int cl0  = (m0.x >> 25) & 3, ta0 = m0.y & 511;
            float4 rv0 = *(const float4*)(rela + rel0 * HD + hc4);
            float4 tv0 = *(const float4*)(temb + ta0 * HD + hc4);
            float vx0 = rv0.x + tv0.x, vy0 = rv0.y + tv0.y;
            float vz0 = rv0.z + tv0.z, vw0 = rv0.w + tv0.w;
            if (!HZ) {
                float4 hv0 = *(const float4*)(hidden_in + (size_t)src0 * HD + hc4);
                vx0 += hv0.x; vy0 += hv0.y; vz0 += hv0.z; vw0 += hv0.w;
            }
            float sA0 = (cl0 == 0) ? sc0 : 0.f;
            float sB0 = (cl0 == 1) ? sc0 : 0.f;
            float sC0 = (cl0 == 2) ? sc0 : 0.f;
            a[rr][0].x = fmaf(sA0, vx0, a[rr][0].x); a[rr][0].y = fmaf(sA0, vy0, a[rr][0].y);
            a[rr][0].z = fmaf(sA0, vz0, a[rr][0].z); a[rr][0].w = fmaf(sA0, vw0, a[rr][0].w);
            a[rr][1].x = fmaf(sB0, vx0, a[rr][1].x); a[rr][1].y = fmaf(sB0, vy0, a[rr][1].y);
            a[rr][1].z = fmaf(sB0, vz0, a[rr][1].z); a[rr][1].w = fmaf(sB0, vw0, a[rr][1].w);
            a[rr][2].x = fmaf(sC0, vx0, a[rr][2].x); a[rr][2].y = fmaf(sC0, vy0, a[rr][2].y);
            a[rr][2].z = fmaf(sC0, vz0, a[rr][2].z); a[rr][2].w = fmaf(sC0, vw0, a[rr][2].w);
        }
    }

    // --- transform, one class slab at a time ---
    float acc[16];
    #pragma unroll
    for (int i = 0; i < 16; ++i) acc[i] = 0.f;
    int h0 = w * 16;

    #pragma unroll
    for (int c = 0; c < 3; ++c) {
        __syncthreads();   // protect previous slab's reads (and entry no-op)
        #pragma unroll
        for (int rr = 0; rr < 4; ++rr) {
            int nl = w * 16 + rr * 4 + g;
            lds_t[(hc4 + 0) * LPITCH + nl] = a[rr][c].x;
            lds_t[(hc4 + 1) * LPITCH + nl] = a[rr][c].y;
            lds_t[(hc4 + 2) * LPITCH + nl] = a[rr][c].z;
            lds_t[(hc4 + 3) * LPITCH + nl] = a[rr][c].w;
        }
        __syncthreads();
        const float* __restrict__ Wb = WT + (c * 64) * 64 + h0;
        #pragma unroll 4
        for (int k = 0; k < 64; ++k) {
            float av = lds_t[k * LPITCH + lane];
            #pragma unroll
            for (int i = 0; i < 16; ++i)
                acc[i] = fmaf(av, Wb[k * 64 + i], acc[i]);
        }
    }

    int node = node0 + lane;
    if (node < NN) {
        float* outp = hidden_out + (size_t)node * 64 + h0;
        #pragma unroll
        for (int qd = 0; qd < 4; ++qd) {
            float4 v = make_float4(fmaxf(acc[qd * 4 + 0], 0.f),
                                   fmaxf(acc[qd * 4 + 1], 0.f),
                                   fmaxf(acc[qd * 4 + 2], 0.f),
                                   fmaxf(acc[qd * 4 + 3], 0.f));
            *(float4*)(outp + qd * 4) = v;
        }
    }
}

// ---------------------------------------------------------------------------
__global__ __launch_bounds__(256) void out_kernel(
    const float* __restrict__ hidden,
    const float* __restrict__ Wc,
    const float* __restrict__ bc,
    float* __restrict__ out)
{
    int i = blockIdx.x * 256 + threadIdx.x;
    if (i >= NOUT) return;
    float r = 0.f;
    if (i < NN) {
        const float4* h4 = (const float4*)(hidden + (size_t)i * 64);
        const float4* w4 = (const float4*)Wc;
        float acc = 0.f;
        #pragma unroll
        for (int q = 0; q < 16; ++q) {
            float4 hv = h4[q], wv = w4[q];
            acc = fmaf(hv.x, wv.x, acc);
            acc = fmaf(hv.y, wv.y, acc);
            acc = fmaf(hv.z, wv.z, acc);
            acc = fmaf(hv.w, wv.w, acc);
        }
        r = acc + bc[0];
    }
    out[i] = r;
}

// ---------------------------------------------------------------------------
extern "C" void kernel_launch(void* const* d_in, const int* in_sizes, int n_in,
                              void* d_out, int out_size, void* d_ws, size_t ws_size,
                              hipStream_t stream)
{
    const int*   batch_idx  = (const int*)d_in[0];
    const int*   src_idx    = (const int*)d_in[1];
    const int*   dst_idx    = (const int*)d_in[2];
    const int*   rel_idx    = (const int*)d_in[3];
    const int*   rel_time   = (const int*)d_in[4];
    const int*   query_rel  = (const int*)d_in[5];
    const float* rela_embed = (const float*)d_in[8];   // [3][231][64]
    const float* time_embed = (const float*)d_in[9];   // [365][64]
    const float* Wp         = (const float*)d_in[10];
    const float* Wn         = (const float*)d_in[11];
    const float* Wf         = (const float*)d_in[12];
    const float* W1         = (const float*)d_in[13];  // [3][5][192]
    const float* W2         = (const float*)d_in[14];  // [3][1][5]
    const float* Wc         = (const float*)d_in[15];  // [64]
    const float* bc         = (const float*)d_in[16];  // [1]
    float* out = (float*)d_out;

    char* ws = (char*)d_ws;
    float* hid0   = (float*)(ws + 0);            // 25.6 MB
    float* hid1   = (float*)(ws + 25600000);     // 25.6 MB
    float* score  = (float*)(ws + 51200000);     //  4.0 MB
    float* WT     = (float*)(ws + 55200000);     //  48 KB
    float* proj   = (float*)(ws + 55300000);     //  3.2 MB
    float* Trel   = (float*)(ws + 58600000);     //  ~22 KB
    float* Tq     = (float*)(ws + 58630000);     //  ~22 KB
    int*   off    = (int*)  (ws + 58660000);     // 400 KB
    int2*  meta   = (int2*) (ws + 59100000);     //  8.0 MB
    // sort temps alias the score region (dead before first score write)
    int*   deg    = (int*)((char*)score + 0);
    int*   tmp    = (int*)((char*)score + 400000);
    int*   cursor = (int*)((char*)score + 800000);
    int*   bsum   = (int*)((char*)score + 1200000);
    int*   bpref  = (int*)((char*)score + 1210000);

    prep_wt_kernel<<<48, 256, 0, stream>>>(Wp, Wn, Wf, WT);
    prep_tables_kernel<<<NL, 256, 0, stream>>>(rela_embed, W1, Trel, Tq);

    // --- counting sort by dst ---
    hipMemsetAsync(deg, 0, NN * sizeof(int), stream);
    hist_kernel<<<(NE + 255) / 256, 256, 0, stream>>>(dst_idx, deg);
    scan1_kernel<<<NBLK1, 256, 0, stream>>>(deg, tmp, bsum);
    scan2_kernel<<<1, 512, 0, stream>>>(bsum, bpref);
    scan3_kernel<<<NBLK1, 256, 0, stream>>>(deg, tmp, bpref, off, cursor);
    sort_scatter_kernel<<<(NE + 255) / 256, 256, 0, stream>>>(
        dst_idx, src_idx, rel_idx, rel_time, batch_idx, query_rel,
        cursor, meta);

    // --- layers (ping-pong: L0 -> hid0, L1 hid0->hid1, L2 hid1->hid0) ---
    for (int i = 0; i < NL; ++i) {
        const float* rela = rela_embed + (size_t)i * NRL * HD;
        const float* W1i  = W1 + (size_t)i * AD * 192;
        const float* W2i  = W2 + (size_t)i * AD;
        const float* Tri  = Trel + (size_t)i * NRL * 8;
        const float* Tqi  = Tq   + (size_t)i * NRL * 8;
        const float* hin  = (i == 1) ? hid0 : hid1;   // unused for i==0
        float*       hout = (i == 0) ? hid0 : ((i == 1) ? hid1 : hid0);
        if (i == 0) {
            score_kernel<true><<<(NE + 255) / 256, 256, 0, stream>>>(
                proj, Tri, Tqi, W2i, meta, score);
            reduce_transform_kernel<true><<<(NN + 63) / 64, 256, 0, stream>>>(
                hin, rela, time_embed, score, meta, off, WT, hout);
        } else {
            proj_kernel<<<(NN + 255) / 256, 256, 0, stream>>>(hin, W1i, proj);
            score_kernel<false><<<(NE + 255) / 256, 256, 0, stream>>>(
                proj, Tri, Tqi, W2i, meta, score);
            reduce_transform_kernel<false><<<(NN + 63) / 64, 256, 0, stream>>>(
                hin, rela, time_embed, score, meta, off, WT, hout);
        }
    }

    out_kernel<<<(NOUT + 255) / 256, 256, 0, stream>>>(hid0, Wc, bc, out);
}